// Round 5
// baseline (207.997 us; speedup 1.0000x reference)
//
#include <hip/hip_runtime.h>
#include <hip/hip_bf16.h>
#include <hip/hip_fp16.h>
#include <stdint.h>

typedef _Float16 f16;
typedef __attribute__((ext_vector_type(8))) _Float16 half8;
typedef __attribute__((ext_vector_type(4))) _Float16 half4;
typedef __attribute__((ext_vector_type(4))) float f32x4;

#define L_SEQ 8192
#define H_DIM 1024
#define P_DIM 512
#define NB 256          // scan blocks
#define TT 32           // scan block length (L/NB)

// async global->LDS, 16B per lane, wave-uniform LDS base + lane*16
#define GL16(gp, lp)                                                        \
  __builtin_amdgcn_global_load_lds(                                          \
      (const __attribute__((address_space(1))) void*)(gp),                   \
      (__attribute__((address_space(3))) void*)(lp), 16, 0, 0)

// ---------------- per-mode constants (f64 internally) ----------------
// cst layout (floats): [0,512): lbar_re  [512,1024): lbar_im
//                      [1024,1536): gamma_re [1536,2048): gamma_im
//                      [2048,2560): lbar^T re [2560,3072): lbar^T im
//                      [3072,4096): S[n] = 2^e_p for n=p and n=512+p (GEMM1 epilogue scale)
//                      [4096,4608): 2^-e_p (folded into W1 so entries are fp16-normal)
__global__ void k_consts(const float* __restrict__ lre, const float* __restrict__ lim,
                         const float* __restrict__ lstep, float* __restrict__ cst) {
  int p = threadIdx.x;  // 512
  double step = exp((double)lstep[p]);
  double ar = (double)lre[p] * step, ai = (double)lim[p] * step;
  double er = exp(ar);
  double lbr = er * cos(ai), lbi = er * sin(ai);
  double nr = lbr - 1.0, ni = lbi;
  double d = (double)lre[p] * (double)lre[p] + (double)lim[p] * (double)lim[p];
  double gr = (nr * (double)lre[p] + ni * (double)lim[p]) / d;
  double gi = (ni * (double)lre[p] - nr * (double)lim[p]) / d;
  cst[p] = (float)lbr; cst[512 + p] = (float)lbi;
  cst[1024 + p] = (float)gr; cst[1536 + p] = (float)gi;
  double aT = ai * (double)TT;
  double eT = exp(ar * (double)TT);
  cst[2048 + p] = (float)(eT * cos(aT));
  cst[2560 + p] = (float)(eT * sin(aT));
  // power-of-2 normalization: |gamma| ~ dt can be 1e-3 -> W1 entries ~2e-5,
  // below fp16 min-normal 6.1e-5 (MFMA flushes denormals). Scale rows to O(1e-2),
  // re-apply the exact 2^e in the f32 GEMM epilogue.
  double gm = fmax(fabs(gr), fabs(gi));
  int e = ilogb(gm) + 1;                 // gm * 2^-e in [0.5, 1)
  float sc = ldexpf(1.0f, e);
  cst[3072 + p] = sc;
  cst[3072 + 512 + p] = sc;
  cst[4096 + p] = ldexpf(1.0f, -e);
}

// W1[n][k] (1024x1024, row-major, fp16): n<512 -> Re(B_bar*2^-e); n>=512 -> Im(B_bar*2^-e)
__global__ void k_w1(const float* __restrict__ B, const float* __restrict__ cst,
                     f16* __restrict__ W1) {
  int idx = blockIdx.x * 256 + threadIdx.x;  // 1M
  int n = idx >> 10, k = idx & 1023;
  int p = n & 511;
  float b0 = B[(size_t)(p * 1024 + k) * 2];
  float b1 = B[(size_t)(p * 1024 + k) * 2 + 1];
  float gr = cst[1024 + p], gi = cst[1536 + p];
  float inv = cst[4096 + p];
  float re = (gr * b0 - gi * b1) * inv;
  float im = (gr * b1 + gi * b0) * inv;
  W1[idx] = (f16)((n < 512) ? re : im);
}

// W2[h][k] (1024x1024, row-major, fp16): k<512 -> 2*C_re[h][k]; k>=512 -> -2*C_im[h][k-512]
__global__ void k_w2(const float* __restrict__ C, f16* __restrict__ W2) {
  int idx = blockIdx.x * 256 + threadIdx.x;
  int h = idx >> 10, k = idx & 1023;
  float v = (k < 512) ? 2.0f * C[(size_t)(h * 512 + k) * 2]
                      : -2.0f * C[(size_t)(h * 512 + (k - 512)) * 2 + 1];
  W2[idx] = (f16)v;
}

// f32 -> fp16, 4 per thread
__global__ void k_cvt(const float* __restrict__ u, f16* __restrict__ uh) {
  int i = blockIdx.x * 256 + threadIdx.x;
  float4 v = reinterpret_cast<const float4*>(u)[i];
  half4 h;
  h.x = (f16)v.x; h.y = (f16)v.y; h.z = (f16)v.z; h.w = (f16)v.w;
  reinterpret_cast<half4*>(uh)[i] = h;
}

// ---------------- GEMM: C[MxN] = A[MxK] * Bm[NxK]^T, fp16 in, f32 out ----------------
// M=8192, N=1024, K=1024. 128x128 tile, 4 waves (2x2), 16x16x32 MFMA, BK=32.
// EPI=0: v *= S[col] (undo W1 row normalization). EPI=1: v += D[col]*U[row][col].
template <int EPI>
__global__ __launch_bounds__(256) void k_gemm(const f16* __restrict__ A,
                                              const f16* __restrict__ Bm,
                                              float* __restrict__ Cm,
                                              const float* __restrict__ D,
                                              const float* __restrict__ U,
                                              const float* __restrict__ S) {
  __shared__ f16 As[128 * 32];
  __shared__ f16 Bs[128 * 32];
  const int tid = threadIdx.x;
  const int wave = tid >> 6, lane = tid & 63;
  const int bm = blockIdx.x >> 3, bn = blockIdx.x & 7;  // 64 x 8 tiles
  const int m0 = bm * 128, n0 = bn * 128;
  const int wr = (wave >> 1) * 64, wc = (wave & 1) * 64;
  const int lr = lane & 15, lg = lane >> 4;
  f32x4 acc[4][4] = {};

  const int c0 = wave * 64 + lane;   // chunk ids
  const int c1 = c0 + 256;
  const int ar0 = c0 >> 2, ak0 = (c0 & 3) * 8;
  const int ar1 = c1 >> 2, ak1 = (c1 & 3) * 8;
  char* lA0 = (char*)As + wave * 1024;
  char* lA1 = (char*)As + 4096 + wave * 1024;
  char* lB0 = (char*)Bs + wave * 1024;
  char* lB1 = (char*)Bs + 4096 + wave * 1024;

  for (int kt = 0; kt < 32; ++kt) {
    const int k0 = kt * 32;
    GL16(A + (size_t)(m0 + ar0) * 1024 + k0 + ak0, lA0);
    GL16(A + (size_t)(m0 + ar1) * 1024 + k0 + ak1, lA1);
    GL16(Bm + (size_t)(n0 + ar0) * 1024 + k0 + ak0, lB0);
    GL16(Bm + (size_t)(n0 + ar1) * 1024 + k0 + ak1, lB1);
    __syncthreads();
    half8 af[4], bf[4];
#pragma unroll
    for (int m = 0; m < 4; ++m)
      af[m] = *(const half8*)&As[(wr + m * 16 + lr) * 32 + lg * 8];
#pragma unroll
    for (int n = 0; n < 4; ++n)
      bf[n] = *(const half8*)&Bs[(wc + n * 16 + lr) * 32 + lg * 8];
#pragma unroll
    for (int m = 0; m < 4; ++m)
#pragma unroll
      for (int n = 0; n < 4; ++n)
        acc[m][n] = __builtin_amdgcn_mfma_f32_16x16x32_f16(af[m], bf[n], acc[m][n], 0, 0, 0);
    __syncthreads();
  }

#pragma unroll
  for (int m = 0; m < 4; ++m)
#pragma unroll
    for (int n = 0; n < 4; ++n) {
      int row = m0 + wr + m * 16 + lg * 4;
      int col = n0 + wc + n * 16 + lr;
      float* cp = Cm + (size_t)row * 1024 + col;
      float scale = (EPI == 0) ? S[col] : 0.0f;
#pragma unroll
      for (int j = 0; j < 4; ++j) {
        float v = acc[m][n][j];
        if (EPI) v += D[col] * U[(size_t)(row + j) * 1024 + col];
        else v *= scale;
        cp[(size_t)j * 1024] = v;
      }
    }
}

// ---------------- blocked scan ----------------
// Bu layout: (L, 1024) f32; col p = re, col 512+p = im
__global__ void k_scanA(const float* __restrict__ Bu, const float* __restrict__ cst,
                        float* __restrict__ carry) {
  int p = threadIdx.x;
  int b = blockIdx.x;
  float lbr = cst[p], lbi = cst[512 + p];
  float xr = 0.f, xi = 0.f;
  const float* row = Bu + (size_t)b * TT * 1024;
  for (int t = 0; t < TT; ++t) {
    float br = row[t * 1024 + p], bi = row[t * 1024 + 512 + p];
    float nxr = lbr * xr - lbi * xi + br;
    float nxi = lbr * xi + lbi * xr + bi;
    xr = nxr; xi = nxi;
  }
  carry[b * 1024 + p] = xr;
  carry[b * 1024 + 512 + p] = xi;
}

__global__ void k_scanB(const float* __restrict__ carry, const float* __restrict__ cst,
                        float* __restrict__ prefix) {
  int p = threadIdx.x;
  float lTr = cst[2048 + p], lTi = cst[2560 + p];
  float xr = 0.f, xi = 0.f;
  for (int b = 0; b < NB; ++b) {
    prefix[b * 1024 + p] = xr;
    prefix[b * 1024 + 512 + p] = xi;
    float cr = carry[b * 1024 + p], ci = carry[b * 1024 + 512 + p];
    float nr = lTr * xr - lTi * xi + cr;
    float ni = lTr * xi + lTi * xr + ci;
    xr = nr; xi = ni;
  }
}

// recompute scan with carry-in, emit fp16 Xcat (L,1024): col p = re, col 512+p = im.
// Last block writes final state; layout chosen by tail = out_size - L*H.
__global__ void k_scanC(const float* __restrict__ Bu, const float* __restrict__ cst,
                        const float* __restrict__ prefix, f16* __restrict__ X,
                        float* __restrict__ fin, int tail) {
  int p = threadIdx.x;
  int b = blockIdx.x;
  float lbr = cst[p], lbi = cst[512 + p];
  float xr = prefix[b * 1024 + p], xi = prefix[b * 1024 + 512 + p];
  const float* row = Bu + (size_t)b * TT * 1024;
  f16* xrow = X + (size_t)b * TT * 1024;
  for (int t = 0; t < TT; ++t) {
    float br = row[t * 1024 + p], bi = row[t * 1024 + 512 + p];
    float nxr = lbr * xr - lbi * xi + br;
    float nxi = lbr * xi + lbi * xr + bi;
    xr = nxr; xi = nxi;
    xrow[t * 1024 + p] = (f16)xr;
    xrow[t * 1024 + 512 + p] = (f16)xi;
  }
  if (b == NB - 1) {
    if (tail >= 1024) {          // complex64 viewed as f32: interleaved re/im
      fin[2 * p] = xr;
      fin[2 * p + 1] = xi;
    } else if (tail >= 512) {    // complex -> f32 astype keeps real part only
      fin[p] = xr;
    }
  }
}

extern "C" void kernel_launch(void* const* d_in, const int* in_sizes, int n_in,
                              void* d_out, int out_size, void* d_ws, size_t ws_size,
                              hipStream_t stream) {
  const float* u    = (const float*)d_in[0];  // (L,H)
  const float* lre  = (const float*)d_in[1];  // (P,)
  const float* lim  = (const float*)d_in[2];  // (P,)
  const float* B    = (const float*)d_in[3];  // (P,H,2)
  const float* C    = (const float*)d_in[4];  // (H,P,2)
  const float* D    = (const float*)d_in[5];  // (H,)
  const float* lstp = (const float*)d_in[6];  // (P,)
  float* out = (float*)d_out;
  int tail = out_size - L_SEQ * H_DIM;

  char* ws = (char*)d_ws;
  float* cst   = (float*)(ws + 0);           // 8192 floats (32 KB, 4608 used)
  f16* uh      = (f16*)(ws + 32768);         // 16 MB
  f16* W1      = (f16*)(ws + 16809984);      // 2 MB
  f16* W2      = (f16*)(ws + 18907136);      // 2 MB
  float* Bu    = (float*)(ws + 21004288);    // 32 MB
  f16* Xc      = (f16*)(ws + 54558720);      // 16 MB
  float* carry = (float*)(ws + 71335936);    // 1 MB
  float* prefix= (float*)(ws + 72384512);    // 1 MB -> end 73433088

  k_consts<<<1, 512, 0, stream>>>(lre, lim, lstp, cst);
  k_w1<<<4096, 256, 0, stream>>>(B, cst, W1);
  k_w2<<<4096, 256, 0, stream>>>(C, W2);
  k_cvt<<<8192, 256, 0, stream>>>(u, uh);
  k_gemm<0><<<512, 256, 0, stream>>>(uh, W1, Bu, nullptr, nullptr, cst + 3072);
  k_scanA<<<NB, 512, 0, stream>>>(Bu, cst, carry);
  k_scanB<<<1, 512, 0, stream>>>(carry, cst, prefix);
  k_scanC<<<NB, 512, 0, stream>>>(Bu, cst, prefix, Xc, out + (size_t)L_SEQ * H_DIM, tail);
  k_gemm<1><<<512, 256, 0, stream>>>(Xc, W2, out, D, u, nullptr);
}

// Round 6
// 184.103 us; speedup vs baseline: 1.1298x; 1.1298x over previous
//
#include <hip/hip_runtime.h>
#include <hip/hip_bf16.h>
#include <hip/hip_fp16.h>
#include <stdint.h>

typedef _Float16 f16;
typedef __attribute__((ext_vector_type(8))) _Float16 half8;
typedef __attribute__((ext_vector_type(4))) _Float16 half4;
typedef __attribute__((ext_vector_type(4))) float f32x4;

#define L_SEQ 8192
#define H_DIM 1024
#define P_DIM 512
#define NB 256          // scan blocks
#define TT 32           // scan block length (L/NB)

// async global->LDS, 16B per lane, wave-uniform LDS base + lane*16
#define GL16(gp, lp)                                                        \
  __builtin_amdgcn_global_load_lds(                                          \
      (const __attribute__((address_space(1))) void*)(gp),                   \
      (__attribute__((address_space(3))) void*)(lp), 16, 0, 0)

// ---------------- per-mode constants (f64 internally) ----------------
// cst layout (floats):
//   [0,512): lbar_re              [512,1024): lbar_im
//   [1024,1536): gamma_re         [1536,2048): gamma_im
//   [3072 + s*1024 + p]: Re(lbar^(32*2^s)), s=0..7
//   [3072 + s*1024 + 512 + p]: Im(lbar^(32*2^s))
//   [11264,12288): S[n]=2^e_p (n=p and 512+p)  — GEMM1 epilogue scale
//   [12288,12800): 2^-e_p — folded into W1 rows (fp16-denormal guard)
__global__ void k_consts(const float* __restrict__ lre, const float* __restrict__ lim,
                         const float* __restrict__ lstep, float* __restrict__ cst) {
  int p = threadIdx.x;  // 512
  double step = exp((double)lstep[p]);
  double ar = (double)lre[p] * step, ai = (double)lim[p] * step;
  double er = exp(ar);
  double lbr = er * cos(ai), lbi = er * sin(ai);
  double nr = lbr - 1.0, ni = lbi;
  double d = (double)lre[p] * (double)lre[p] + (double)lim[p] * (double)lim[p];
  double gr = (nr * (double)lre[p] + ni * (double)lim[p]) / d;
  double gi = (ni * (double)lre[p] - nr * (double)lim[p]) / d;
  cst[p] = (float)lbr; cst[512 + p] = (float)lbi;
  cst[1024 + p] = (float)gr; cst[1536 + p] = (float)gi;
#pragma unroll
  for (int s = 0; s < 8; ++s) {
    double n = 32.0 * (double)(1 << s);
    double eT = exp(ar * n);
    cst[3072 + s * 1024 + p]       = (float)(eT * cos(ai * n));
    cst[3072 + s * 1024 + 512 + p] = (float)(eT * sin(ai * n));
  }
  // power-of-2 normalization: |gamma| ~ dt can be 1e-3 -> W1 entries ~2e-5,
  // below fp16 min-normal 6.1e-5 (MFMA flushes denormals). Scale rows to O(1e-2),
  // re-apply the exact 2^e in the f32 GEMM1 epilogue.
  double gm = fmax(fabs(gr), fabs(gi));
  int e = ilogb(gm) + 1;
  float sc = ldexpf(1.0f, e);
  cst[11264 + p] = sc;
  cst[11264 + 512 + p] = sc;
  cst[12288 + p] = ldexpf(1.0f, -e);
}

// fused prep: blocks [0,4096) W1-gen, [4096,8192) W2-gen, [8192,16384) u->f16 cvt
// W1[n][k]: n<512 -> Re(gamma*B * 2^-e); n>=512 -> Im(...)
// W2[h][k]: k<512 -> 2*C_re[h][k]; k>=512 -> -2*C_im[h][k-512]
__global__ void k_prep(const float* __restrict__ B, const float* __restrict__ C,
                       const float* __restrict__ u, const float* __restrict__ cst,
                       f16* __restrict__ W1, f16* __restrict__ W2,
                       f16* __restrict__ uh) {
  int blk = blockIdx.x;
  if (blk < 4096) {
    int idx = blk * 256 + threadIdx.x;  // 1M
    int n = idx >> 10, k = idx & 1023;
    int p = n & 511;
    float b0 = B[(size_t)(p * 1024 + k) * 2];
    float b1 = B[(size_t)(p * 1024 + k) * 2 + 1];
    float gr = cst[1024 + p], gi = cst[1536 + p];
    float inv = cst[12288 + p];
    float re = (gr * b0 - gi * b1) * inv;
    float im = (gr * b1 + gi * b0) * inv;
    W1[idx] = (f16)((n < 512) ? re : im);
  } else if (blk < 8192) {
    int idx = (blk - 4096) * 256 + threadIdx.x;
    int h = idx >> 10, k = idx & 1023;
    float v = (k < 512) ? 2.0f * C[(size_t)(h * 512 + k) * 2]
                        : -2.0f * C[(size_t)(h * 512 + (k - 512)) * 2 + 1];
    W2[idx] = (f16)v;
  } else {
    int i = (blk - 8192) * 256 + threadIdx.x;  // 2M float4 over 8M floats
    float4 v = reinterpret_cast<const float4*>(u)[i];
    half4 h;
    h.x = (f16)v.x; h.y = (f16)v.y; h.z = (f16)v.z; h.w = (f16)v.w;
    reinterpret_cast<half4*>(uh)[i] = h;
  }
}

// ---------------- GEMM: C[MxN] = A[MxK] * Bm[NxK]^T, fp16 in ----------------
// M=8192, N=1024, K=1024. 128x128 tile, 4 waves (2x2), 16x16x32 MFMA, BK=32.
// EPI=0: out f16 = acc * S[col]  (Bu, scale undoes W1 row normalization)
// EPI=1: out f32 = acc + D[col]*Uh[row][col]  (final projection + D-skip)
template <int EPI>
__global__ __launch_bounds__(256) void k_gemm(const f16* __restrict__ A,
                                              const f16* __restrict__ Bm,
                                              float* __restrict__ CmF,
                                              f16* __restrict__ CmH,
                                              const float* __restrict__ D,
                                              const f16* __restrict__ Uh,
                                              const float* __restrict__ S) {
  __shared__ f16 As[128 * 32];
  __shared__ f16 Bs[128 * 32];
  const int tid = threadIdx.x;
  const int wave = tid >> 6, lane = tid & 63;
  const int bm = blockIdx.x >> 3, bn = blockIdx.x & 7;  // 64 x 8 tiles
  const int m0 = bm * 128, n0 = bn * 128;
  const int wr = (wave >> 1) * 64, wc = (wave & 1) * 64;
  const int lr = lane & 15, lg = lane >> 4;
  f32x4 acc[4][4] = {};

  const int c0 = wave * 64 + lane;   // chunk ids
  const int c1 = c0 + 256;
  const int ar0 = c0 >> 2, ak0 = (c0 & 3) * 8;
  const int ar1 = c1 >> 2, ak1 = (c1 & 3) * 8;
  char* lA0 = (char*)As + wave * 1024;
  char* lA1 = (char*)As + 4096 + wave * 1024;
  char* lB0 = (char*)Bs + wave * 1024;
  char* lB1 = (char*)Bs + 4096 + wave * 1024;

  for (int kt = 0; kt < 32; ++kt) {
    const int k0 = kt * 32;
    GL16(A + (size_t)(m0 + ar0) * 1024 + k0 + ak0, lA0);
    GL16(A + (size_t)(m0 + ar1) * 1024 + k0 + ak1, lA1);
    GL16(Bm + (size_t)(n0 + ar0) * 1024 + k0 + ak0, lB0);
    GL16(Bm + (size_t)(n0 + ar1) * 1024 + k0 + ak1, lB1);
    __syncthreads();
    half8 af[4], bf[4];
#pragma unroll
    for (int m = 0; m < 4; ++m)
      af[m] = *(const half8*)&As[(wr + m * 16 + lr) * 32 + lg * 8];
#pragma unroll
    for (int n = 0; n < 4; ++n)
      bf[n] = *(const half8*)&Bs[(wc + n * 16 + lr) * 32 + lg * 8];
#pragma unroll
    for (int m = 0; m < 4; ++m)
#pragma unroll
      for (int n = 0; n < 4; ++n)
        acc[m][n] = __builtin_amdgcn_mfma_f32_16x16x32_f16(af[m], bf[n], acc[m][n], 0, 0, 0);
    __syncthreads();
  }

#pragma unroll
  for (int m = 0; m < 4; ++m)
#pragma unroll
    for (int n = 0; n < 4; ++n) {
      int row = m0 + wr + m * 16 + lg * 4;
      int col = n0 + wc + n * 16 + lr;
      float scale = (EPI == 0) ? S[col] : 0.0f;
#pragma unroll
      for (int j = 0; j < 4; ++j) {
        float v = acc[m][n][j];
        if (EPI) {
          v += D[col] * (float)Uh[(size_t)(row + j) * 1024 + col];
          CmF[(size_t)(row + j) * 1024 + col] = v;
        } else {
          CmH[(size_t)(row + j) * 1024 + col] = (f16)(v * scale);
        }
      }
    }
}

// ---------------- blocked scan ----------------
// Bu layout: (L, 1024) f16; col p = re, col 512+p = im
__global__ void k_scanA(const f16* __restrict__ Bu, const float* __restrict__ cst,
                        float* __restrict__ carry) {
  int p = threadIdx.x;
  int b = blockIdx.x;
  float lbr = cst[p], lbi = cst[512 + p];
  float xr = 0.f, xi = 0.f;
  const f16* row = Bu + (size_t)b * TT * 1024;
  for (int t = 0; t < TT; ++t) {
    float br = (float)row[t * 1024 + p], bi = (float)row[t * 1024 + 512 + p];
    float nxr = lbr * xr - lbi * xi + br;
    float nxi = lbr * xi + lbi * xr + bi;
    xr = nxr; xi = nxi;
  }
  carry[b * 1024 + p] = xr;
  carry[b * 1024 + 512 + p] = xi;
}

// parallel carry-scan: one block per mode p (512 blocks), 256 threads (one per b).
// Kogge-Stone inclusive scan of x_{b} = sum_{j<=b} lbar^(32(b-j)) carry_j, then
// prefix[b] = inclusive[b-1] (state entering block b).
__global__ void k_scanB(const float* __restrict__ carry, const float* __restrict__ cst,
                        float* __restrict__ prefix) {
  __shared__ float sre[256], sim[256];
  int p = blockIdx.x;
  int b = threadIdx.x;
  float xr = carry[b * 1024 + p], xi = carry[b * 1024 + 512 + p];
  sre[b] = xr; sim[b] = xi;
  __syncthreads();
#pragma unroll
  for (int s = 0; s < 8; ++s) {
    float pr = cst[3072 + s * 1024 + p];
    float pi = cst[3072 + s * 1024 + 512 + p];
    int off = 1 << s;
    float ar = 0.f, ai = 0.f;
    if (b >= off) { ar = sre[b - off]; ai = sim[b - off]; }
    __syncthreads();
    xr += pr * ar - pi * ai;
    xi += pr * ai + pi * ar;
    sre[b] = xr; sim[b] = xi;
    __syncthreads();
  }
  float er = 0.f, ei = 0.f;
  if (b > 0) { er = sre[b - 1]; ei = sim[b - 1]; }
  prefix[b * 1024 + p] = er;
  prefix[b * 1024 + 512 + p] = ei;
}

// recompute scan with carry-in, emit fp16 Xcat (L,1024): col p = re, col 512+p = im.
// Last block writes final state; layout chosen by tail = out_size - L*H.
__global__ void k_scanC(const f16* __restrict__ Bu, const float* __restrict__ cst,
                        const float* __restrict__ prefix, f16* __restrict__ X,
                        float* __restrict__ fin, int tail) {
  int p = threadIdx.x;
  int b = blockIdx.x;
  float lbr = cst[p], lbi = cst[512 + p];
  float xr = prefix[b * 1024 + p], xi = prefix[b * 1024 + 512 + p];
  const f16* row = Bu + (size_t)b * TT * 1024;
  f16* xrow = X + (size_t)b * TT * 1024;
  for (int t = 0; t < TT; ++t) {
    float br = (float)row[t * 1024 + p], bi = (float)row[t * 1024 + 512 + p];
    float nxr = lbr * xr - lbi * xi + br;
    float nxi = lbr * xi + lbi * xr + bi;
    xr = nxr; xi = nxi;
    xrow[t * 1024 + p] = (f16)xr;
    xrow[t * 1024 + 512 + p] = (f16)xi;
  }
  if (b == NB - 1) {
    if (tail >= 1024) {          // complex64 viewed as f32: interleaved re/im
      fin[2 * p] = xr;
      fin[2 * p + 1] = xi;
    } else if (tail >= 512) {    // complex -> f32 keeps real part only
      fin[p] = xr;
    }
  }
}

extern "C" void kernel_launch(void* const* d_in, const int* in_sizes, int n_in,
                              void* d_out, int out_size, void* d_ws, size_t ws_size,
                              hipStream_t stream) {
  const float* u    = (const float*)d_in[0];  // (L,H)
  const float* lre  = (const float*)d_in[1];  // (P,)
  const float* lim  = (const float*)d_in[2];  // (P,)
  const float* B    = (const float*)d_in[3];  // (P,H,2)
  const float* C    = (const float*)d_in[4];  // (H,P,2)
  const float* D    = (const float*)d_in[5];  // (H,)
  const float* lstp = (const float*)d_in[6];  // (P,)
  float* out = (float*)d_out;
  int tail = out_size - L_SEQ * H_DIM;

  char* ws = (char*)d_ws;
  float* cst   = (float*)(ws + 0);            // 16384 floats (64 KB; 12800 used)
  f16* uh      = (f16*)(ws + 65536);          // 16 MB
  f16* W1      = (f16*)(ws + 16842752);       // 2 MB
  f16* W2      = (f16*)(ws + 18939904);       // 2 MB
  f16* Bu      = (f16*)(ws + 21037056);       // 16 MB
  f16* Xc      = (f16*)(ws + 37814272);       // 16 MB
  float* carry = (float*)(ws + 54591488);     // 1 MB
  float* prefix= (float*)(ws + 55639040);     // 1 MB -> end 56686592

  k_consts<<<1, 512, 0, stream>>>(lre, lim, lstp, cst);
  k_prep<<<16384, 256, 0, stream>>>(B, C, u, cst, W1, W2, uh);
  k_gemm<0><<<512, 256, 0, stream>>>(uh, W1, nullptr, Bu, nullptr, nullptr, cst + 11264);
  k_scanA<<<NB, 512, 0, stream>>>(Bu, cst, carry);
  k_scanB<<<512, 256, 0, stream>>>(carry, cst, prefix);
  k_scanC<<<NB, 512, 0, stream>>>(Bu, cst, prefix, Xc, out + (size_t)L_SEQ * H_DIM, tail);
  k_gemm<1><<<512, 256, 0, stream>>>(Xc, W2, out, nullptr, D, uh, nullptr);
}